// Round 1
// baseline (374.893 us; speedup 1.0000x reference)
//
#include <hip/hip_runtime.h>
#include <hip/hip_bf16.h>

// FraudDetectionHybrid: h1=tanh(x@W1^T+b1); h2=tanh(h1@W2^T+b2);
// sq_ij=|h2_i|^2+|h2_j|^2-2*h2_i.h2_j; out=exp(-g*sq)@Wc^T+bc
// N=4096, HID=4096, IN_DIM=512. Workspace needed: ~104 MB.

#define NROWS 4096
#define HID   4096
#define INDIM 512
#define GAMMA_F 5e-4f

typedef float f32x4 __attribute__((ext_vector_type(4)));
typedef short bf16x8 __attribute__((ext_vector_type(8)));   // 8 bf16 in 4 VGPRs

__device__ __forceinline__ unsigned short f2bf_rne(float f) {
  union { float f; unsigned int u; } v; v.f = f;
  unsigned int r = v.u + 0x7FFFu + ((v.u >> 16) & 1u);
  return (unsigned short)(r >> 16);
}
__device__ __forceinline__ float bf2f(unsigned short u) {
  union { unsigned int u; float f; } v; v.u = ((unsigned int)u) << 16; return v.f;
}

__global__ void cast_f32_bf16(const float* __restrict__ src,
                              unsigned short* __restrict__ dst, int n4) {
  int i = blockIdx.x * blockDim.x + threadIdx.x;
  if (i >= n4) return;
  float4 v = ((const float4*)src)[i];
  ushort4 o;
  o.x = f2bf_rne(v.x); o.y = f2bf_rne(v.y);
  o.z = f2bf_rne(v.z); o.w = f2bf_rne(v.w);
  ((ushort4*)dst)[i] = o;
}

__global__ void init_out(float* __restrict__ out, const float* __restrict__ bc, int n) {
  int i = blockIdx.x * blockDim.x + threadIdx.x;
  if (i < n) out[i] = bc[0];
}

// one block (256 thr) per row; 4096 bf16 = 16 per thread
__global__ void row_norms(const unsigned short* __restrict__ H, float* __restrict__ norms) {
  int row = blockIdx.x;
  int tid = threadIdx.x;
  const unsigned short* p = H + (size_t)row * HID + tid * 16;
  uint4 a = *(const uint4*)p;
  uint4 b = *(const uint4*)(p + 8);
  float s = 0.f;
#define ACC(u) { float lo = bf2f((unsigned short)((u) & 0xffffu)); \
                 float hi = bf2f((unsigned short)((u) >> 16));     \
                 s += lo * lo + hi * hi; }
  ACC(a.x) ACC(a.y) ACC(a.z) ACC(a.w) ACC(b.x) ACC(b.y) ACC(b.z) ACC(b.w)
#undef ACC
  for (int m = 1; m <= 32; m <<= 1) s += __shfl_xor(s, m);
  __shared__ float wsum[4];
  int lane = tid & 63, w = tid >> 6;
  if (lane == 0) wsum[w] = s;
  __syncthreads();
  if (tid == 0) norms[row] = wsum[0] + wsum[1] + wsum[2] + wsum[3];
}

__device__ __forceinline__ void gload16(const void* g, void* l) {
  __builtin_amdgcn_global_load_lds(
      (const __attribute__((address_space(1))) void*)g,
      (__attribute__((address_space(3))) void*)l, 16, 0, 0);
}

// NT GEMM: D = A[M,K] * B[N,K]^T, 128x128 tile, BK=32, 4 waves (2x2), m97 structure.
// LDS tiles hold chunk-swizzled rows (chunk ^= (row>>1)&3) staged via
// pre-swizzled GLOBAL source (linear LDS dest, rule #21) -> ~2-way bank aliasing (free).
// EPI 0: Hout = bf16(tanh(acc + bias[col]))
// EPI 1: out[row] += sum_col exp(-g*(n_row+n_col-2*acc)) * Wc[col]   (atomicAdd)
template <int EPI>
__global__ __launch_bounds__(256, 2)
void gemm_nt(const unsigned short* __restrict__ A, const unsigned short* __restrict__ B,
             int K, int N,
             const float* __restrict__ bias, unsigned short* __restrict__ Hout,
             const float* __restrict__ norms, const float* __restrict__ Wc,
             float* __restrict__ out) {
  __shared__ __align__(16) unsigned short As[128 * 32];
  __shared__ __align__(16) unsigned short Bs[128 * 32];

  const int tid  = threadIdx.x;
  const int lane = tid & 63;
  const int wave = tid >> 6;
  const int wr = wave >> 1, wc = wave & 1;      // 2x2 wave grid, 64x64 each
  const int fr = lane & 15, fq = lane >> 4;     // fragment row/quad

  // bijective XCD swizzle (grid is 1024, %8==0)
  const int nwg = gridDim.x;
  const int cpx = nwg >> 3;
  const int bid = blockIdx.x;
  const int swz = (bid & 7) * cpx + (bid >> 3);
  const int nbx = N >> 7;
  const int brow = (swz / nbx) << 7;
  const int bcol = (swz % nbx) << 7;

  f32x4 acc[4][4] = {};

  for (int k0 = 0; k0 < K; k0 += 32) {
    __syncthreads();  // previous tile's ds_reads done before overwrite
#pragma unroll
    for (int q = 0; q < 2; ++q) {
      int idx = q * 256 + tid;           // 16B chunk index within 128x32 tile
      int row = idx >> 2, c = idx & 3;
      int col = (c ^ ((row >> 1) & 3)) << 3;  // pre-swizzled global chunk
      gload16(A + (size_t)(brow + row) * K + k0 + col,
              &As[(q * 256 + wave * 64) * 8]);
      gload16(B + (size_t)(bcol + row) * K + k0 + col,
              &Bs[(q * 256 + wave * 64) * 8]);
    }
    __syncthreads();  // compiler drains vmcnt(0) before barrier

    bf16x8 af[4], bfrag[4];
#pragma unroll
    for (int mi = 0; mi < 4; ++mi) {
      int row = wr * 64 + mi * 16 + fr;
      af[mi] = *(const bf16x8*)&As[row * 32 + ((fq ^ ((row >> 1) & 3)) << 3)];
    }
#pragma unroll
    for (int nj = 0; nj < 4; ++nj) {
      int row = wc * 64 + nj * 16 + fr;
      bfrag[nj] = *(const bf16x8*)&Bs[row * 32 + ((fq ^ ((row >> 1) & 3)) << 3)];
    }
#pragma unroll
    for (int mi = 0; mi < 4; ++mi)
#pragma unroll
      for (int nj = 0; nj < 4; ++nj)
        acc[mi][nj] = __builtin_amdgcn_mfma_f32_16x16x32_bf16(
            af[mi], bfrag[nj], acc[mi][nj], 0, 0, 0);
  }

  // C/D layout (m89-verified): col = lane&15, row = (lane>>4)*4 + reg
  if (EPI == 0) {
#pragma unroll
    for (int nj = 0; nj < 4; ++nj) {
      int col = bcol + wc * 64 + nj * 16 + fr;
      float bv = bias[col];
#pragma unroll
      for (int mi = 0; mi < 4; ++mi) {
        int row0 = brow + wr * 64 + mi * 16 + fq * 4;
#pragma unroll
        for (int rr = 0; rr < 4; ++rr) {
          float v = tanhf(acc[mi][nj][rr] + bv);
          Hout[(size_t)(row0 + rr) * N + col] = f2bf_rne(v);
        }
      }
    }
  } else {
    float ncol[4], wcv[4];
#pragma unroll
    for (int nj = 0; nj < 4; ++nj) {
      int col = bcol + wc * 64 + nj * 16 + fr;
      ncol[nj] = norms[col];
      wcv[nj]  = Wc[col];
    }
#pragma unroll
    for (int mi = 0; mi < 4; ++mi) {
#pragma unroll
      for (int rr = 0; rr < 4; ++rr) {
        int row = brow + wr * 64 + mi * 16 + fq * 4 + rr;
        float nrow = norms[row];
        float part = 0.f;
#pragma unroll
        for (int nj = 0; nj < 4; ++nj) {
          float sq = nrow + ncol[nj] - 2.0f * acc[mi][nj][rr];
          part += __expf(-GAMMA_F * sq) * wcv[nj];
        }
        // reduce across the 16 lanes sharing this row (xor bits 0..3)
        part += __shfl_xor(part, 1);
        part += __shfl_xor(part, 2);
        part += __shfl_xor(part, 4);
        part += __shfl_xor(part, 8);
        if (fr == 0) atomicAdd(&out[row], part);
      }
    }
  }
}

extern "C" void kernel_launch(void* const* d_in, const int* in_sizes, int n_in,
                              void* d_out, int out_size, void* d_ws, size_t ws_size,
                              hipStream_t stream) {
  const float* x  = (const float*)d_in[0];  // [4096,512]
  const float* W1 = (const float*)d_in[1];  // [4096,512]
  const float* b1 = (const float*)d_in[2];  // [4096]
  const float* W2 = (const float*)d_in[3];  // [4096,4096]
  const float* b2 = (const float*)d_in[4];  // [4096]
  const float* Wc = (const float*)d_in[5];  // [1,4096]
  const float* bc = (const float*)d_in[6];  // [1]
  float* out = (float*)d_out;               // [4096,1]

  char* ws = (char*)d_ws;
  unsigned short* xb  = (unsigned short*)ws; ws += (size_t)NROWS * INDIM * 2;
  unsigned short* w1b = (unsigned short*)ws; ws += (size_t)HID * INDIM * 2;
  unsigned short* w2b = (unsigned short*)ws; ws += (size_t)HID * HID * 2;
  unsigned short* h1  = (unsigned short*)ws; ws += (size_t)NROWS * HID * 2;
  unsigned short* h2  = (unsigned short*)ws; ws += (size_t)NROWS * HID * 2;
  float* norms = (float*)ws;                 ws += (size_t)NROWS * 4;

  // casts to bf16
  {
    int n4 = NROWS * INDIM / 4;
    cast_f32_bf16<<<(n4 + 255) / 256, 256, 0, stream>>>(x, xb, n4);
    cast_f32_bf16<<<(n4 + 255) / 256, 256, 0, stream>>>(W1, w1b, n4);
    int m4 = HID * HID / 4;
    cast_f32_bf16<<<(m4 + 255) / 256, 256, 0, stream>>>(W2, w2b, m4);
  }

  const int grid = (NROWS / 128) * (HID / 128);  // 1024

  // h1 = tanh(x @ W1^T + b1)
  gemm_nt<0><<<grid, 256, 0, stream>>>(xb, w1b, INDIM, HID, b1, h1,
                                       nullptr, nullptr, nullptr);
  // h2 = tanh(h1 @ W2^T + b2)
  gemm_nt<0><<<grid, 256, 0, stream>>>(h1, w2b, HID, HID, b2, h2,
                                       nullptr, nullptr, nullptr);
  // row norms of h2
  row_norms<<<NROWS, 256, 0, stream>>>(h2, norms);
  // out = bc
  init_out<<<(NROWS + 255) / 256, 256, 0, stream>>>(out, bc, NROWS);
  // out[i] += sum_j exp(-g*(n_i+n_j-2*h2_i.h2_j)) * Wc[j]
  gemm_nt<1><<<grid, 256, 0, stream>>>(h2, h2, HID, HID, nullptr, nullptr,
                                       norms, Wc, out);
}

// Round 2
// 334.083 us; speedup vs baseline: 1.1222x; 1.1222x over previous
//
#include <hip/hip_runtime.h>
#include <hip/hip_bf16.h>

// FraudDetectionHybrid: h1=tanh(x@W1^T+b1); h2=tanh(h1@W2^T+b2);
// sq_ij=|h2_i|^2+|h2_j|^2-2*h2_i.h2_j; out=exp(-g*sq)@Wc^T+bc
// 256x256 8-phase GEMM (T2+T3+T4+T5), counted vmcnt, k-half-split staging.

#define NROWS 4096
#define HID   4096
#define INDIM 512
#define GAMMA_F 5e-4f

typedef float f32x4 __attribute__((ext_vector_type(4)));
typedef short bf16x8 __attribute__((ext_vector_type(8)));

__device__ __forceinline__ unsigned short f2bf_rne(float f) {
  union { float f; unsigned int u; } v; v.f = f;
  unsigned int r = v.u + 0x7FFFu + ((v.u >> 16) & 1u);
  return (unsigned short)(r >> 16);
}
__device__ __forceinline__ float bf2f(unsigned short u) {
  union { unsigned int u; float f; } v; v.u = ((unsigned int)u) << 16; return v.f;
}

__global__ void cast_f32_bf16(const float* __restrict__ src,
                              unsigned short* __restrict__ dst, int n4) {
  int i = blockIdx.x * blockDim.x + threadIdx.x;
  if (i >= n4) return;
  float4 v = ((const float4*)src)[i];
  ushort4 o;
  o.x = f2bf_rne(v.x); o.y = f2bf_rne(v.y);
  o.z = f2bf_rne(v.z); o.w = f2bf_rne(v.w);
  ((ushort4*)dst)[i] = o;
}

__global__ void init_out(float* __restrict__ out, const float* __restrict__ bc, int n) {
  int i = blockIdx.x * blockDim.x + threadIdx.x;
  if (i < n) out[i] = bc[0];
}

// one block (256 thr) per row; 4096 bf16 = 16 per thread
__global__ void row_norms(const unsigned short* __restrict__ H, float* __restrict__ norms) {
  int row = blockIdx.x;
  int tid = threadIdx.x;
  const unsigned short* p = H + (size_t)row * HID + tid * 16;
  uint4 a = *(const uint4*)p;
  uint4 b = *(const uint4*)(p + 8);
  float s = 0.f;
#define ACC(u) { float lo = bf2f((unsigned short)((u) & 0xffffu)); \
                 float hi = bf2f((unsigned short)((u) >> 16));     \
                 s += lo * lo + hi * hi; }
  ACC(a.x) ACC(a.y) ACC(a.z) ACC(a.w) ACC(b.x) ACC(b.y) ACC(b.z) ACC(b.w)
#undef ACC
  for (int m = 1; m <= 32; m <<= 1) s += __shfl_xor(s, m);
  __shared__ float wsum[4];
  int lane = tid & 63, w = tid >> 6;
  if (lane == 0) wsum[w] = s;
  __syncthreads();
  if (tid == 0) norms[row] = wsum[0] + wsum[1] + wsum[2] + wsum[3];
}

__device__ __forceinline__ void gload16(const void* g, void* l) {
  __builtin_amdgcn_global_load_lds(
      (const __attribute__((address_space(1))) void*)g,
      (__attribute__((address_space(3))) void*)l, 16, 0, 0);
}

// ---------------------------------------------------------------------------
// 256x256 NT GEMM, BK=64, 8 waves (2Mx4N), 8-phase (4 phases per K-tile),
// counted vmcnt(8), raw s_barrier, setprio around MFMA clusters.
// LDS: [dbuf][khalf] 256x32 bf16 halves for A and B = 128 KiB.
// Swizzle: storage 16B-chunk cg holds global chunk cg ^ ((row>>1)&3)
// (pre-swizzled global source; same XOR on ds_read) -> <=2-way banks (free).
// EPI 0: Hout = bf16(tanh(acc + bias[col]))
// EPI 1: out[row] += sum_col exp(-g*(n_row+n_col-2*acc)) * Wc[col]
// ---------------------------------------------------------------------------
template <int EPI>
__global__ __launch_bounds__(512, 2)
void gemm256(const unsigned short* __restrict__ A, const unsigned short* __restrict__ B,
             int K, int N,
             const float* __restrict__ bias, unsigned short* __restrict__ Hout,
             const float* __restrict__ norms, const float* __restrict__ Wc,
             float* __restrict__ out) {
  __shared__ __align__(16) unsigned short As[2][2][256 * 32];
  __shared__ __align__(16) unsigned short Bs[2][2][256 * 32];

  const int tid  = threadIdx.x;
  const int lane = tid & 63;
  const int wave = tid >> 6;
  const int wr = wave >> 2, wc = wave & 3;   // 2x4 wave grid, 128x64 out each
  const int fr = lane & 15, fq = lane >> 4;

  // bijective XCD swizzle (grid 256, %8==0)
  const int nwg = gridDim.x;
  const int cpx = nwg >> 3;
  const int bid = blockIdx.x;
  const int swz = (bid & 7) * cpx + (bid >> 3);
  const int nbx = N >> 8;
  const int brow = (swz / nbx) << 8;
  const int bcol = (swz % nbx) << 8;

  // staging map: chunk idx = l*512 + tid; r=idx>>2, cg=idx&3 (4 chunks/row of 32 bf16)
  const int i0 = tid, i1 = 512 + tid;
  const int r0 = i0 >> 2, r1 = i1 >> 2;
  const int sc0 = ((i0 & 3) ^ ((r0 >> 1) & 3)) << 3;   // pre-swizzled bf16 col
  const int sc1 = ((i1 & 3) ^ ((r1 >> 1) & 3)) << 3;
  const int ld0 = (wave * 64) * 8;                      // wave-uniform LDS chunk base
  const int ld1 = (512 + wave * 64) * 8;
  const unsigned short* a0 = A + (size_t)(brow + r0) * K + sc0;
  const unsigned short* a1 = A + (size_t)(brow + r1) * K + sc1;
  const unsigned short* b0 = B + (size_t)(bcol + r0) * K + sc0;
  const unsigned short* b1 = B + (size_t)(bcol + r1) * K + sc1;

#define STAGE_A(p, kh, tt) do { int kk = (tt) * 64 + (kh) * 32;  \
    gload16(a0 + kk, &As[p][kh][ld0]);                           \
    gload16(a1 + kk, &As[p][kh][ld1]); } while (0)
#define STAGE_B(p, kh, tt) do { int kk = (tt) * 64 + (kh) * 32;  \
    gload16(b0 + kk, &Bs[p][kh][ld0]);                           \
    gload16(b1 + kk, &Bs[p][kh][ld1]); } while (0)

  // fragment LDS offsets (loop-invariant)
  int aoff[8], boff[4];
#pragma unroll
  for (int mi = 0; mi < 8; ++mi) {
    int row = wr * 128 + mi * 16 + fr;
    aoff[mi] = row * 32 + ((fq ^ ((row >> 1) & 3)) << 3);
  }
#pragma unroll
  for (int nj = 0; nj < 4; ++nj) {
    int row = wc * 64 + nj * 16 + fr;
    boff[nj] = row * 32 + ((fq ^ ((row >> 1) & 3)) << 3);
  }

  const int NT = K >> 6;  // K-tiles (even: K % 128 == 0)

  // prologue: tile0 fully + tile1 k0-halves = 12 loads/thread
  STAGE_A(0, 0, 0); STAGE_B(0, 0, 0);
  STAGE_A(0, 1, 0); STAGE_B(0, 1, 0);
  STAGE_A(1, 0, 1); STAGE_B(1, 0, 1);
  asm volatile("s_waitcnt vmcnt(8)" ::: "memory");  // tile0 k0 landed
  __builtin_amdgcn_s_barrier();

  f32x4 acc[8][4] = {};

  for (int t = 0; t < NT; ++t) {
    const int p = t & 1;
    int t1 = t + 1; if (t1 >= NT) t1 -= NT;   // wrapped dummy stages keep
    int t2 = t + 2; if (t2 >= NT) t2 -= NT;   // vmcnt counts uniform (NT even)
    const int p1 = p ^ 1;

    bf16x8 af[4], bfr[4];

    // ---- P1: kh=0, mi 0-3 (8 ds_read) ----
#pragma unroll
    for (int mi = 0; mi < 4; ++mi) af[mi] = *(const bf16x8*)&As[p][0][aoff[mi]];
#pragma unroll
    for (int nj = 0; nj < 4; ++nj) bfr[nj] = *(const bf16x8*)&Bs[p][0][boff[nj]];
    STAGE_A(p1, 1, t1);
    __builtin_amdgcn_s_barrier();
    asm volatile("s_waitcnt lgkmcnt(0)" ::: "memory");
    __builtin_amdgcn_sched_barrier(0);
    __builtin_amdgcn_s_setprio(1);
#pragma unroll
    for (int mi = 0; mi < 4; ++mi)
#pragma unroll
      for (int nj = 0; nj < 4; ++nj)
        acc[mi][nj] = __builtin_amdgcn_mfma_f32_16x16x32_bf16(af[mi], bfr[nj], acc[mi][nj], 0, 0, 0);
    __builtin_amdgcn_s_setprio(0);
    __builtin_amdgcn_s_barrier();

    // ---- P2: kh=0, mi 4-7 (4 ds_read; B reused) ----
#pragma unroll
    for (int mi = 0; mi < 4; ++mi) af[mi] = *(const bf16x8*)&As[p][0][aoff[mi + 4]];
    STAGE_B(p1, 1, t1);
    __builtin_amdgcn_s_barrier();
    asm volatile("s_waitcnt lgkmcnt(0)" ::: "memory");
    __builtin_amdgcn_sched_barrier(0);
    __builtin_amdgcn_s_setprio(1);
#pragma unroll
    for (int mi = 0; mi < 4; ++mi)
#pragma unroll
      for (int nj = 0; nj < 4; ++nj)
        acc[mi + 4][nj] = __builtin_amdgcn_mfma_f32_16x16x32_bf16(af[mi], bfr[nj], acc[mi + 4][nj], 0, 0, 0);
    __builtin_amdgcn_s_setprio(0);
    asm volatile("s_waitcnt vmcnt(8)" ::: "memory");  // k1(t) landed for P3
    __builtin_amdgcn_s_barrier();

    // ---- P3: kh=1, mi 0-3 (8 ds_read) ----
#pragma unroll
    for (int mi = 0; mi < 4; ++mi) af[mi] = *(const bf16x8*)&As[p][1][aoff[mi]];
#pragma unroll
    for (int nj = 0; nj < 4; ++nj) bfr[nj] = *(const bf16x8*)&Bs[p][1][boff[nj]];
    STAGE_A(p, 0, t2);
    __builtin_amdgcn_s_barrier();
    asm volatile("s_waitcnt lgkmcnt(0)" ::: "memory");
    __builtin_amdgcn_sched_barrier(0);
    __builtin_amdgcn_s_setprio(1);
#pragma unroll
    for (int mi = 0; mi < 4; ++mi)
#pragma unroll
      for (int nj = 0; nj < 4; ++nj)
        acc[mi][nj] = __builtin_amdgcn_mfma_f32_16x16x32_bf16(af[mi], bfr[nj], acc[mi][nj], 0, 0, 0);
    __builtin_amdgcn_s_setprio(0);
    __builtin_amdgcn_s_barrier();

    // ---- P4: kh=1, mi 4-7 (4 ds_read) ----
#pragma unroll
    for (int mi = 0; mi < 4; ++mi) af[mi] = *(const bf16x8*)&As[p][1][aoff[mi + 4]];
    STAGE_B(p, 0, t2);
    __builtin_amdgcn_s_barrier();
    asm volatile("s_waitcnt lgkmcnt(0)" ::: "memory");
    __builtin_amdgcn_sched_barrier(0);
    __builtin_amdgcn_s_setprio(1);
#pragma unroll
    for (int mi = 0; mi < 4; ++mi)
#pragma unroll
      for (int nj = 0; nj < 4; ++nj)
        acc[mi + 4][nj] = __builtin_amdgcn_mfma_f32_16x16x32_bf16(af[mi], bfr[nj], acc[mi + 4][nj], 0, 0, 0);
    __builtin_amdgcn_s_setprio(0);
    asm volatile("s_waitcnt vmcnt(8)" ::: "memory");  // k0(t+1) landed for next P1
    __builtin_amdgcn_s_barrier();
  }
  asm volatile("s_waitcnt vmcnt(0)" ::: "memory");  // drain wrapped dummy stages

  // C/D layout (m89-verified): col = lane&15, row = (lane>>4)*4 + reg
  if (EPI == 0) {
#pragma unroll
    for (int nj = 0; nj < 4; ++nj) {
      int col = bcol + wc * 64 + nj * 16 + fr;
      float bv = bias[col];
#pragma unroll
      for (int mi = 0; mi < 8; ++mi) {
        int row0 = brow + wr * 128 + mi * 16 + fq * 4;
#pragma unroll
        for (int rr = 0; rr < 4; ++rr) {
          float v = tanhf(acc[mi][nj][rr] + bv);
          Hout[(size_t)(row0 + rr) * N + col] = f2bf_rne(v);
        }
      }
    }
  } else {
    float ncol[4], wcv[4];
#pragma unroll
    for (int nj = 0; nj < 4; ++nj) {
      int col = bcol + wc * 64 + nj * 16 + fr;
      ncol[nj] = norms[col];
      wcv[nj]  = Wc[col];
    }
#pragma unroll
    for (int mi = 0; mi < 8; ++mi) {
#pragma unroll
      for (int rr = 0; rr < 4; ++rr) {
        int row = brow + wr * 128 + mi * 16 + fq * 4 + rr;
        float nrow = norms[row];
        float part = 0.f;
#pragma unroll
        for (int nj = 0; nj < 4; ++nj) {
          float sq = nrow + ncol[nj] - 2.0f * acc[mi][nj][rr];
          part += __expf(-GAMMA_F * sq) * wcv[nj];
        }
        part += __shfl_xor(part, 1);
        part += __shfl_xor(part, 2);
        part += __shfl_xor(part, 4);
        part += __shfl_xor(part, 8);
        if (fr == 0) atomicAdd(&out[row], part);
      }
    }
  }
#undef STAGE_A
#undef STAGE_B
}

extern "C" void kernel_launch(void* const* d_in, const int* in_sizes, int n_in,
                              void* d_out, int out_size, void* d_ws, size_t ws_size,
                              hipStream_t stream) {
  const float* x  = (const float*)d_in[0];  // [4096,512]
  const float* W1 = (const float*)d_in[1];  // [4096,512]
  const float* b1 = (const float*)d_in[2];  // [4096]
  const float* W2 = (const float*)d_in[3];  // [4096,4096]
  const float* b2 = (const float*)d_in[4];  // [4096]
  const float* Wc = (const float*)d_in[5];  // [1,4096]
  const float* bc = (const float*)d_in[6];  // [1]
  float* out = (float*)d_out;               // [4096,1]

  char* ws = (char*)d_ws;
  unsigned short* xb  = (unsigned short*)ws; ws += (size_t)NROWS * INDIM * 2;
  unsigned short* w1b = (unsigned short*)ws; ws += (size_t)HID * INDIM * 2;
  unsigned short* w2b = (unsigned short*)ws; ws += (size_t)HID * HID * 2;
  unsigned short* h1  = (unsigned short*)ws; ws += (size_t)NROWS * HID * 2;
  unsigned short* h2  = (unsigned short*)ws; ws += (size_t)NROWS * HID * 2;
  float* norms = (float*)ws;                 ws += (size_t)NROWS * 4;

  {
    int n4 = NROWS * INDIM / 4;
    cast_f32_bf16<<<(n4 + 255) / 256, 256, 0, stream>>>(x, xb, n4);
    cast_f32_bf16<<<(n4 + 255) / 256, 256, 0, stream>>>(W1, w1b, n4);
    int m4 = HID * HID / 4;
    cast_f32_bf16<<<(m4 + 255) / 256, 256, 0, stream>>>(W2, w2b, m4);
  }

  const int grid = (NROWS / 256) * (HID / 256);  // 256

  // h1 = tanh(x @ W1^T + b1)
  gemm256<0><<<grid, 512, 0, stream>>>(xb, w1b, INDIM, HID, b1, h1,
                                       nullptr, nullptr, nullptr);
  // h2 = tanh(h1 @ W2^T + b2)
  gemm256<0><<<grid, 512, 0, stream>>>(h1, w2b, HID, HID, b2, h2,
                                       nullptr, nullptr, nullptr);
  // row norms of h2
  row_norms<<<NROWS, 256, 0, stream>>>(h2, norms);
  // out = bc
  init_out<<<(NROWS + 255) / 256, 256, 0, stream>>>(out, bc, NROWS);
  // out[i] += sum_j exp(-g*(n_i+n_j-2*h2_i.h2_j)) * Wc[j]
  gemm256<1><<<grid, 512, 0, stream>>>(h2, h2, HID, HID, nullptr, nullptr,
                                       norms, Wc, out);
}

// Round 3
// 295.814 us; speedup vs baseline: 1.2673x; 1.1294x over previous
//
#include <hip/hip_runtime.h>
#include <hip/hip_bf16.h>

// FraudDetectionHybrid: h1=tanh(x@W1^T+b1); h2=tanh(h1@W2^T+b2);
// sq_ij=|h2_i|^2+|h2_j|^2-2*h2_i.h2_j; out=exp(-g*sq)@Wc^T+bc
// GEMM1/2: 256x256 8-phase bf16 MFMA. Gram: SYMMETRIC -> triangular
// 128x128 tiles (528 blocks), each exp() feeds both out[row] and out[col].
// row_norms fused into GEMM2 epilogue.

#define NROWS 4096
#define HID   4096
#define INDIM 512
#define GAMMA_F 5e-4f

typedef float f32x4 __attribute__((ext_vector_type(4)));
typedef short bf16x8 __attribute__((ext_vector_type(8)));

__device__ __forceinline__ unsigned short f2bf_rne(float f) {
  union { float f; unsigned int u; } v; v.f = f;
  unsigned int r = v.u + 0x7FFFu + ((v.u >> 16) & 1u);
  return (unsigned short)(r >> 16);
}
__device__ __forceinline__ float bf2f(unsigned short u) {
  union { unsigned int u; float f; } v; v.u = ((unsigned int)u) << 16; return v.f;
}

__global__ void cast_f32_bf16(const float* __restrict__ src,
                              unsigned short* __restrict__ dst, int n4) {
  int i = blockIdx.x * blockDim.x + threadIdx.x;
  if (i >= n4) return;
  float4 v = ((const float4*)src)[i];
  ushort4 o;
  o.x = f2bf_rne(v.x); o.y = f2bf_rne(v.y);
  o.z = f2bf_rne(v.z); o.w = f2bf_rne(v.w);
  ((ushort4*)dst)[i] = o;
}

// out[i] = bc; norms[i] = 0  (both length NROWS)
__global__ void init_vecs(float* __restrict__ out, float* __restrict__ norms,
                          const float* __restrict__ bc, int n) {
  int i = blockIdx.x * blockDim.x + threadIdx.x;
  if (i < n) { out[i] = bc[0]; norms[i] = 0.f; }
}

__device__ __forceinline__ void gload16(const void* g, void* l) {
  __builtin_amdgcn_global_load_lds(
      (const __attribute__((address_space(1))) void*)g,
      (__attribute__((address_space(3))) void*)l, 16, 0, 0);
}

// ---------------------------------------------------------------------------
// 256x256 NT GEMM, BK=64, 8 waves (2Mx4N), 4 phases/K-tile, counted vmcnt(8).
// EPI 0: Hout = bf16(tanh(acc + bias[col]))
// EPI 2: same + norms_out[row] += sum_col tanh^2 (fused row_norms)
// ---------------------------------------------------------------------------
template <int EPI>
__global__ __launch_bounds__(512, 2)
void gemm256(const unsigned short* __restrict__ A, const unsigned short* __restrict__ B,
             int K, int N,
             const float* __restrict__ bias, unsigned short* __restrict__ Hout,
             float* __restrict__ norms_out) {
  __shared__ __align__(16) unsigned short As[2][2][256 * 32];
  __shared__ __align__(16) unsigned short Bs[2][2][256 * 32];

  const int tid  = threadIdx.x;
  const int lane = tid & 63;
  const int wave = tid >> 6;
  const int wr = wave >> 2, wc = wave & 3;   // 2x4 wave grid, 128x64 out each
  const int fr = lane & 15, fq = lane >> 4;

  const int nwg = gridDim.x;
  const int cpx = nwg >> 3;
  const int bid = blockIdx.x;
  const int swz = (bid & 7) * cpx + (bid >> 3);
  const int nbx = N >> 8;
  const int brow = (swz / nbx) << 8;
  const int bcol = (swz % nbx) << 8;

  const int i0 = tid, i1 = 512 + tid;
  const int r0 = i0 >> 2, r1 = i1 >> 2;
  const int sc0 = ((i0 & 3) ^ ((r0 >> 1) & 3)) << 3;
  const int sc1 = ((i1 & 3) ^ ((r1 >> 1) & 3)) << 3;
  const int ld0 = (wave * 64) * 8;
  const int ld1 = (512 + wave * 64) * 8;
  const unsigned short* a0 = A + (size_t)(brow + r0) * K + sc0;
  const unsigned short* a1 = A + (size_t)(brow + r1) * K + sc1;
  const unsigned short* b0 = B + (size_t)(bcol + r0) * K + sc0;
  const unsigned short* b1 = B + (size_t)(bcol + r1) * K + sc1;

#define STAGE_A(p, kh, tt) do { int kk = (tt) * 64 + (kh) * 32;  \
    gload16(a0 + kk, &As[p][kh][ld0]);                           \
    gload16(a1 + kk, &As[p][kh][ld1]); } while (0)
#define STAGE_B(p, kh, tt) do { int kk = (tt) * 64 + (kh) * 32;  \
    gload16(b0 + kk, &Bs[p][kh][ld0]);                           \
    gload16(b1 + kk, &Bs[p][kh][ld1]); } while (0)

  int aoff[8], boff[4];
#pragma unroll
  for (int mi = 0; mi < 8; ++mi) {
    int row = wr * 128 + mi * 16 + fr;
    aoff[mi] = row * 32 + ((fq ^ ((row >> 1) & 3)) << 3);
  }
#pragma unroll
  for (int nj = 0; nj < 4; ++nj) {
    int row = wc * 64 + nj * 16 + fr;
    boff[nj] = row * 32 + ((fq ^ ((row >> 1) & 3)) << 3);
  }

  const int NT = K >> 6;

  STAGE_A(0, 0, 0); STAGE_B(0, 0, 0);
  STAGE_A(0, 1, 0); STAGE_B(0, 1, 0);
  STAGE_A(1, 0, 1); STAGE_B(1, 0, 1);
  asm volatile("s_waitcnt vmcnt(8)" ::: "memory");
  __builtin_amdgcn_s_barrier();

  f32x4 acc[8][4] = {};

  for (int t = 0; t < NT; ++t) {
    const int p = t & 1;
    int t1 = t + 1; if (t1 >= NT) t1 -= NT;
    int t2 = t + 2; if (t2 >= NT) t2 -= NT;
    const int p1 = p ^ 1;

    bf16x8 af[4], bfr[4];

    // ---- P1: kh=0, mi 0-3 ----
#pragma unroll
    for (int mi = 0; mi < 4; ++mi) af[mi] = *(const bf16x8*)&As[p][0][aoff[mi]];
#pragma unroll
    for (int nj = 0; nj < 4; ++nj) bfr[nj] = *(const bf16x8*)&Bs[p][0][boff[nj]];
    STAGE_A(p1, 1, t1);
    __builtin_amdgcn_s_barrier();
    asm volatile("s_waitcnt lgkmcnt(0)" ::: "memory");
    __builtin_amdgcn_sched_barrier(0);
    __builtin_amdgcn_s_setprio(1);
#pragma unroll
    for (int mi = 0; mi < 4; ++mi)
#pragma unroll
      for (int nj = 0; nj < 4; ++nj)
        acc[mi][nj] = __builtin_amdgcn_mfma_f32_16x16x32_bf16(af[mi], bfr[nj], acc[mi][nj], 0, 0, 0);
    __builtin_amdgcn_s_setprio(0);
    __builtin_amdgcn_s_barrier();

    // ---- P2: kh=0, mi 4-7 ----
#pragma unroll
    for (int mi = 0; mi < 4; ++mi) af[mi] = *(const bf16x8*)&As[p][0][aoff[mi + 4]];
    STAGE_B(p1, 1, t1);
    __builtin_amdgcn_s_barrier();
    asm volatile("s_waitcnt lgkmcnt(0)" ::: "memory");
    __builtin_amdgcn_sched_barrier(0);
    __builtin_amdgcn_s_setprio(1);
#pragma unroll
    for (int mi = 0; mi < 4; ++mi)
#pragma unroll
      for (int nj = 0; nj < 4; ++nj)
        acc[mi + 4][nj] = __builtin_amdgcn_mfma_f32_16x16x32_bf16(af[mi], bfr[nj], acc[mi + 4][nj], 0, 0, 0);
    __builtin_amdgcn_s_setprio(0);
    asm volatile("s_waitcnt vmcnt(8)" ::: "memory");
    __builtin_amdgcn_s_barrier();

    // ---- P3: kh=1, mi 0-3 ----
#pragma unroll
    for (int mi = 0; mi < 4; ++mi) af[mi] = *(const bf16x8*)&As[p][1][aoff[mi]];
#pragma unroll
    for (int nj = 0; nj < 4; ++nj) bfr[nj] = *(const bf16x8*)&Bs[p][1][boff[nj]];
    STAGE_A(p, 0, t2);
    __builtin_amdgcn_s_barrier();
    asm volatile("s_waitcnt lgkmcnt(0)" ::: "memory");
    __builtin_amdgcn_sched_barrier(0);
    __builtin_amdgcn_s_setprio(1);
#pragma unroll
    for (int mi = 0; mi < 4; ++mi)
#pragma unroll
      for (int nj = 0; nj < 4; ++nj)
        acc[mi][nj] = __builtin_amdgcn_mfma_f32_16x16x32_bf16(af[mi], bfr[nj], acc[mi][nj], 0, 0, 0);
    __builtin_amdgcn_s_setprio(0);
    __builtin_amdgcn_s_barrier();

    // ---- P4: kh=1, mi 4-7 ----
#pragma unroll
    for (int mi = 0; mi < 4; ++mi) af[mi] = *(const bf16x8*)&As[p][1][aoff[mi + 4]];
    STAGE_B(p, 0, t2);
    __builtin_amdgcn_s_barrier();
    asm volatile("s_waitcnt lgkmcnt(0)" ::: "memory");
    __builtin_amdgcn_sched_barrier(0);
    __builtin_amdgcn_s_setprio(1);
#pragma unroll
    for (int mi = 0; mi < 4; ++mi)
#pragma unroll
      for (int nj = 0; nj < 4; ++nj)
        acc[mi + 4][nj] = __builtin_amdgcn_mfma_f32_16x16x32_bf16(af[mi], bfr[nj], acc[mi + 4][nj], 0, 0, 0);
    __builtin_amdgcn_s_setprio(0);
    asm volatile("s_waitcnt vmcnt(8)" ::: "memory");
    __builtin_amdgcn_s_barrier();
  }
  asm volatile("s_waitcnt vmcnt(0)" ::: "memory");

  // C/D layout: col = lane&15, row = (lane>>4)*4 + reg
  float bv[4];
#pragma unroll
  for (int nj = 0; nj < 4; ++nj) bv[nj] = bias[bcol + wc * 64 + nj * 16 + fr];
#pragma unroll
  for (int mi = 0; mi < 8; ++mi) {
    int row0 = brow + wr * 128 + mi * 16 + fq * 4;
#pragma unroll
    for (int rr = 0; rr < 4; ++rr) {
      float ns = 0.f;
#pragma unroll
      for (int nj = 0; nj < 4; ++nj) {
        float v = tanhf(acc[mi][nj][rr] + bv[nj]);
        Hout[(size_t)(row0 + rr) * N + (bcol + wc * 64 + nj * 16 + fr)] = f2bf_rne(v);
        if (EPI == 2) ns += v * v;
      }
      if (EPI == 2) {
        ns += __shfl_xor(ns, 1);
        ns += __shfl_xor(ns, 2);
        ns += __shfl_xor(ns, 4);
        ns += __shfl_xor(ns, 8);
        if (fr == 0) atomicAdd(&norms_out[row0 + rr], ns);
      }
    }
  }
#undef STAGE_A
#undef STAGE_B
}

// ---------------------------------------------------------------------------
// Triangular gram: 128x128 tiles over the lower triangle (528 blocks),
// 4 waves (2x2), simple 2-barrier K-loop (proven round-1 structure).
// Off-diagonal tiles: each exp(-g*sq_rc) contributes Wc[c] to out[r] AND
// Wc[r] to out[c]. Diagonal tiles: row direction only.
// ---------------------------------------------------------------------------
__global__ __launch_bounds__(256, 2)
void gram_tri(const unsigned short* __restrict__ H, int K,
              const float* __restrict__ norms, const float* __restrict__ Wc,
              float* __restrict__ out) {
  __shared__ __align__(16) unsigned short As[128 * 32];
  __shared__ __align__(16) unsigned short Bs[128 * 32];

  const int tid  = threadIdx.x;
  const int lane = tid & 63;
  const int wave = tid >> 6;
  const int wr = wave >> 1, wc = wave & 1;
  const int fr = lane & 15, fq = lane >> 4;

  // XCD swizzle (528 = 8*66) then lower-triangle decode
  const int bid = blockIdx.x;
  const int swz = (bid & 7) * 66 + (bid >> 3);
  int I = (int)((sqrtf(8.0f * (float)swz + 1.0f) - 1.0f) * 0.5f);
  while ((I + 1) * (I + 2) / 2 <= swz) ++I;
  while (I * (I + 1) / 2 > swz) --I;
  const int J = swz - I * (I + 1) / 2;
  const int brow = I << 7, bcol = J << 7;
  const bool diag = (I == J);

  f32x4 acc[4][4] = {};

  for (int k0 = 0; k0 < K; k0 += 32) {
    __syncthreads();
#pragma unroll
    for (int q = 0; q < 2; ++q) {
      int idx = q * 256 + tid;
      int row = idx >> 2, c = idx & 3;
      int col = (c ^ ((row >> 1) & 3)) << 3;
      gload16(H + (size_t)(brow + row) * K + k0 + col, &As[(q * 256 + wave * 64) * 8]);
      gload16(H + (size_t)(bcol + row) * K + k0 + col, &Bs[(q * 256 + wave * 64) * 8]);
    }
    __syncthreads();

    bf16x8 af[4], bfrag[4];
#pragma unroll
    for (int mi = 0; mi < 4; ++mi) {
      int row = wr * 64 + mi * 16 + fr;
      af[mi] = *(const bf16x8*)&As[row * 32 + ((fq ^ ((row >> 1) & 3)) << 3)];
    }
#pragma unroll
    for (int nj = 0; nj < 4; ++nj) {
      int row = wc * 64 + nj * 16 + fr;
      bfrag[nj] = *(const bf16x8*)&Bs[row * 32 + ((fq ^ ((row >> 1) & 3)) << 3)];
    }
#pragma unroll
    for (int mi = 0; mi < 4; ++mi)
#pragma unroll
      for (int nj = 0; nj < 4; ++nj)
        acc[mi][nj] = __builtin_amdgcn_mfma_f32_16x16x32_bf16(af[mi], bfrag[nj], acc[mi][nj], 0, 0, 0);
  }

  // epilogue: e = exp(-g*(n_r + n_c - 2*acc)); dual reduction
  float ncol[4], wcv[4];
#pragma unroll
  for (int nj = 0; nj < 4; ++nj) {
    int col = bcol + wc * 64 + nj * 16 + fr;
    ncol[nj] = norms[col];
    wcv[nj]  = Wc[col];
  }
  float colpart[4] = {0.f, 0.f, 0.f, 0.f};
#pragma unroll
  for (int mi = 0; mi < 4; ++mi) {
    int row0 = brow + wr * 64 + mi * 16 + fq * 4;
    float4 nr4  = *(const float4*)&norms[row0];
    float4 wcr4 = *(const float4*)&Wc[row0];
#pragma unroll
    for (int rr = 0; rr < 4; ++rr) {
      float nrow = (rr == 0) ? nr4.x : (rr == 1) ? nr4.y : (rr == 2) ? nr4.z : nr4.w;
      float wrow = (rr == 0) ? wcr4.x : (rr == 1) ? wcr4.y : (rr == 2) ? wcr4.z : wcr4.w;
      float rowpart = 0.f;
#pragma unroll
      for (int nj = 0; nj < 4; ++nj) {
        float sq = nrow + ncol[nj] - 2.0f * acc[mi][nj][rr];
        float e = __expf(-GAMMA_F * sq);
        rowpart += e * wcv[nj];
        colpart[nj] += e * wrow;     // harmless for diag (discarded below)
      }
      rowpart += __shfl_xor(rowpart, 1);
      rowpart += __shfl_xor(rowpart, 2);
      rowpart += __shfl_xor(rowpart, 4);
      rowpart += __shfl_xor(rowpart, 8);
      if (fr == 0) atomicAdd(&out[row0 + rr], rowpart);
    }
  }
  if (!diag) {
#pragma unroll
    for (int nj = 0; nj < 4; ++nj) {
      colpart[nj] += __shfl_xor(colpart[nj], 16);
      colpart[nj] += __shfl_xor(colpart[nj], 32);
      if (fq == 0) atomicAdd(&out[bcol + wc * 64 + nj * 16 + fr], colpart[nj]);
    }
  }
}

extern "C" void kernel_launch(void* const* d_in, const int* in_sizes, int n_in,
                              void* d_out, int out_size, void* d_ws, size_t ws_size,
                              hipStream_t stream) {
  const float* x  = (const float*)d_in[0];  // [4096,512]
  const float* W1 = (const float*)d_in[1];  // [4096,512]
  const float* b1 = (const float*)d_in[2];  // [4096]
  const float* W2 = (const float*)d_in[3];  // [4096,4096]
  const float* b2 = (const float*)d_in[4];  // [4096]
  const float* Wc = (const float*)d_in[5];  // [1,4096]
  const float* bc = (const float*)d_in[6];  // [1]
  float* out = (float*)d_out;               // [4096,1]

  char* ws = (char*)d_ws;
  unsigned short* xb  = (unsigned short*)ws; ws += (size_t)NROWS * INDIM * 2;
  unsigned short* w1b = (unsigned short*)ws; ws += (size_t)HID * INDIM * 2;
  unsigned short* w2b = (unsigned short*)ws; ws += (size_t)HID * HID * 2;
  unsigned short* h1  = (unsigned short*)ws; ws += (size_t)NROWS * HID * 2;
  unsigned short* h2  = (unsigned short*)ws; ws += (size_t)NROWS * HID * 2;
  float* norms = (float*)ws;                 ws += (size_t)NROWS * 4;

  {
    int n4 = NROWS * INDIM / 4;
    cast_f32_bf16<<<(n4 + 255) / 256, 256, 0, stream>>>(x, xb, n4);
    cast_f32_bf16<<<(n4 + 255) / 256, 256, 0, stream>>>(W1, w1b, n4);
    int m4 = HID * HID / 4;
    cast_f32_bf16<<<(m4 + 255) / 256, 256, 0, stream>>>(W2, w2b, m4);
  }

  const int grid = (NROWS / 256) * (HID / 256);  // 256

  // h1 = tanh(x @ W1^T + b1)
  gemm256<0><<<grid, 512, 0, stream>>>(xb, w1b, INDIM, HID, b1, h1, nullptr);
  // out = bc; norms = 0  (before GEMM2's norm atomics and gram's out atomics)
  init_vecs<<<(NROWS + 255) / 256, 256, 0, stream>>>(out, norms, bc, NROWS);
  // h2 = tanh(h1 @ W2^T + b2), norms[row] += sum tanh^2 fused
  gemm256<2><<<grid, 512, 0, stream>>>(h1, w2b, HID, HID, b2, h2, norms);
  // triangular gram + classifier
  gram_tri<<<528, 256, 0, stream>>>(h2, HID, norms, Wc, out);
}